// Round 10
// baseline (3875.745 us; speedup 1.0000x reference)
//
#include <hip/hip_runtime.h>

#define BATCH 4
#define NPTS  2048
#define DIM   16
#define REGEPS 0.01f
#define DECAYF 0.9f
#define MINUPD 0.01f
#define MAXIT  50
#define LOGN   7.62461898616f   // ln(2048)
#define L2E    1.44269504089f   // log2(e)
#define LN2    0.69314718056f

typedef float v2f __attribute__((ext_vector_type(2)));

// ---- workspace layout (units of 4 bytes) ----
#define OFF_SX    0
#define OFF_SQ    (BATCH*NPTS*DIM)            // 131072
#define OFF_F     (OFF_SQ + BATCH*NPTS)       // 139264
#define OFF_G     (OFF_F + BATCH*NPTS)        // 147456
#define OFF_MEAN  (OFF_G + BATCH*NPTS)        // 155648
#define OFF_SCALE (OFF_MEAN + BATCH*DIM)      // 155712
#define OFF_EPS0  (OFF_SCALE + BATCH)         // 155716
// per-batch sync region: 128 ints (512B), 256B-aligned. R3-proven layout:
//   [0]   : arrive counter (acq_rel RMW by 64 blocks)   } line 0
//   [2,3] : upd dual slots (uint atomicMax, gated)      } line 0
//   [32]  : epoch (1 writer, relaxed pollers, acq exit) } line 1
#define OFF_SYNC  155776                      // 623104 B

// ============================================================
// Preprocess (proven): mean/std/scale, sx, sq, extent->eps0,
// zero f/g, init sync region.  grid = BATCH x 256
// ============================================================
__global__ __launch_bounds__(256) void ot_preproc(const float* __restrict__ state,
                                                  float* __restrict__ ws) {
  const int b = blockIdx.x;
  const int tid = threadIdx.x;
  __shared__ float s_sum[16][17];
  __shared__ float s_sq[16][17];
  __shared__ float s_mean[16];
  __shared__ float s_red[8];
  __shared__ float s_scale_sh;

  const float* st = state + b * NPTS * DIM;
  const int d = tid & 15, grp = tid >> 4;
  float sm = 0.f, s2 = 0.f;
  for (int n = grp; n < NPTS; n += 16) {
    float x = st[n * DIM + d];
    sm += x; s2 += x * x;
  }
  s_sum[grp][d] = sm; s_sq[grp][d] = s2;
  __syncthreads();
  if (tid < 16) {
    float S = 0.f, Q = 0.f;
    for (int g2 = 0; g2 < 16; ++g2) { S += s_sum[g2][tid]; Q += s_sq[g2][tid]; }
    float mean = S * (1.0f / NPTS);
    float var  = fmaxf(Q * (1.0f / NPTS) - mean * mean, 0.f);
    float sd   = sqrtf(var);
    s_mean[tid] = mean;
    ws[OFF_MEAN + b * DIM + tid] = mean;
    s_sum[0][tid] = sd;
  }
  __syncthreads();
  if (tid == 0) {
    float dm = 0.f;
    for (int d2 = 0; d2 < 16; ++d2) dm = fmaxf(dm, s_sum[0][d2]);
    if (dm == 0.f) dm = 1.f;
    float scale = dm * 4.0f;          // * sqrt(D=16)
    s_scale_sh = scale;
    ws[OFF_SCALE + b] = scale;
  }
  __syncthreads();

  const float inv_scale = 1.0f / s_scale_sh;
  float vmin = 3.0e38f, vmax = -3.0e38f;
  float* sx = ws + OFF_SX + b * NPTS * DIM;
  float* sq = ws + OFF_SQ + b * NPTS;
  for (int n = tid; n < NPTS; n += 256) {
    const float4* rp = (const float4*)(st + n * DIM);
    float4 xs0 = rp[0], xs1 = rp[1], xs2 = rp[2], xs3 = rp[3];
    float xv[16] = {xs0.x,xs0.y,xs0.z,xs0.w, xs1.x,xs1.y,xs1.z,xs1.w,
                    xs2.x,xs2.y,xs2.z,xs2.w, xs3.x,xs3.y,xs3.z,xs3.w};
    float ov[16];
    float q = 0.f;
    #pragma unroll
    for (int e = 0; e < 16; ++e) {
      float v = (xv[e] - s_mean[e]) * inv_scale;
      ov[e] = v; q += v * v;
      vmin = fminf(vmin, v); vmax = fmaxf(vmax, v);
    }
    float4* op = (float4*)(sx + n * DIM);
    op[0] = make_float4(ov[0],ov[1],ov[2],ov[3]);
    op[1] = make_float4(ov[4],ov[5],ov[6],ov[7]);
    op[2] = make_float4(ov[8],ov[9],ov[10],ov[11]);
    op[3] = make_float4(ov[12],ov[13],ov[14],ov[15]);
    sq[n] = q;
  }
  float* fv = ws + OFF_F + b * NPTS;
  float* gv = ws + OFF_G + b * NPTS;
  for (int n = tid; n < NPTS; n += 256) { fv[n] = 0.f; gv[n] = 0.f; }
  #pragma unroll
  for (int off = 32; off > 0; off >>= 1) {
    vmin = fminf(vmin, __shfl_xor(vmin, off));
    vmax = fmaxf(vmax, __shfl_xor(vmax, off));
  }
  const int wv = tid >> 6, ln = tid & 63;
  if (ln == 0) { s_red[wv] = vmin; s_red[4 + wv] = vmax; }
  __syncthreads();
  if (tid == 0) {
    float mn = fminf(fminf(s_red[0], s_red[1]), fminf(s_red[2], s_red[3]));
    float mx = fmaxf(fmaxf(s_red[4], s_red[5]), fmaxf(s_red[6], s_red[7]));
    ws[OFF_EPS0 + b] = mx - mn;
  }
  // zero sync region (arrive/upd/epoch)
  int* sy = (int*)ws + OFF_SYNC + b * 128;
  for (int k = tid; k < 128; k += 256) sy[k] = 0;
}

// ============================================================
// Coherent (cross-XCD) 16B load: bypass L1/L2 (proven R3/R4/R8 form).
// ============================================================
__device__ __forceinline__ float4 load_f4_coherent(const float* p) {
  float4 v;
  asm volatile("global_load_dwordx4 %0, %1, off sc0 sc1\n\t"
               "s_waitcnt vmcnt(0)"
               : "=v"(v) : "v"(p) : "memory");
  return v;
}

// ============================================================
// R3-proven epoch-broadcast barrier among 64 blocks of one batch.
// arrive: acq_rel RMW line. epoch: 1 writer, relaxed read-only pollers
// (no per-poll invalidate), one ACQUIRE load on exit. Measured (R3):
// 33.5us/phase total, FETCH 17MB — best sync structure so far.
// ============================================================
__device__ __forceinline__ void batch_barrier(int* sy, int ph) {
  __syncthreads();
  if (threadIdx.x == 0) {
    int* arrive = sy;
    int* epoch  = sy + 32;
    const int old = __hip_atomic_fetch_add(arrive, 1, __ATOMIC_ACQ_REL,
                                           __HIP_MEMORY_SCOPE_AGENT);
    if (old == 64 * ph - 1) {
      __hip_atomic_store(epoch, ph, __ATOMIC_RELEASE, __HIP_MEMORY_SCOPE_AGENT);
    } else {
      while (__hip_atomic_load(epoch, __ATOMIC_RELAXED, __HIP_MEMORY_SCOPE_AGENT) < ph)
        __builtin_amdgcn_s_sleep(2);
      (void)__hip_atomic_load(epoch, __ATOMIC_ACQUIRE, __HIP_MEMORY_SCOPE_AGENT);
    }
  }
  __syncthreads();
}

// ============================================================
// LSE sweep: float4 (b128) LDS loads — proven conflict-free pattern —
// reinterpreted as v2f pairs in-register for v_pk_fma_f32.
// sxr holds 2*L2E*sx_i; a2 carries (src-q)*L2E/eps [+wl2].
// ============================================================
__device__ __forceinline__ void lse_sweep(const float* __restrict__ s_xt,
                                          const float* __restrict__ s_a2,
                                          const float (&sxr)[4][16],
                                          float inv_eps, int l,
                                          float (&M)[4], float (&S)[4]) {
  const v2f inv2 = { inv_eps, inv_eps };
  #pragma unroll
  for (int r = 0; r < 4; ++r) { M[r] = -3.0e38f; S[r] = 0.0f; }
  for (int c = 0; c < 8; ++c) {
    const int jb = c * 256 + 4 * l;
    const float4 af = *(const float4*)(s_a2 + jb);
    const v2f av0 = { af.x, af.y }, av1 = { af.z, af.w };
    v2f acc[4][2];
    {
      const float4 xf = *(const float4*)(s_xt + jb);   // dd = 0, ds_read_b128
      const v2f x0 = { xf.x, xf.y }, x1 = { xf.z, xf.w };
      #pragma unroll
      for (int r = 0; r < 4; ++r) {
        const v2f sv = { sxr[r][0], sxr[r][0] };
        acc[r][0] = x0 * sv;
        acc[r][1] = x1 * sv;
      }
    }
    #pragma unroll
    for (int dd = 1; dd < 16; ++dd) {
      const float4 xf = *(const float4*)(s_xt + dd * 2048 + jb);
      const v2f x0 = { xf.x, xf.y }, x1 = { xf.z, xf.w };
      #pragma unroll
      for (int r = 0; r < 4; ++r) {
        const v2f sv = { sxr[r][dd], sxr[r][dd] };
        acc[r][0] = __builtin_elementwise_fma(x0, sv, acc[r][0]);
        acc[r][1] = __builtin_elementwise_fma(x1, sv, acc[r][1]);
      }
    }
    #pragma unroll
    for (int r = 0; r < 4; ++r) {
      const v2f v01 = __builtin_elementwise_fma(acc[r][0], inv2, av0);
      const v2f v23 = __builtin_elementwise_fma(acc[r][1], inv2, av1);
      const float v0 = v01.x, v1 = v01.y, v2 = v23.x, v3 = v23.y;
      const float cmx = fmaxf(fmaxf(v0, v1), fmaxf(v2, v3));
      const float nm = fmaxf(M[r], cmx);
      const float e0 = exp2f(M[r] - nm);
      const float sa = exp2f(v0-nm) + exp2f(v1-nm) + exp2f(v2-nm) + exp2f(v3-nm);
      S[r] = fmaf(S[r], e0, sa);
      M[r] = nm;
    }
  }
}

__device__ __forceinline__ void lse_butterfly(float (&M)[4], float (&S)[4]) {
  #pragma unroll
  for (int off = 1; off < 64; off <<= 1) {
    #pragma unroll
    for (int r = 0; r < 4; ++r) {
      const float om = __shfl_xor(M[r], off);
      const float os = __shfl_xor(S[r], off);
      const float nm = fmaxf(M[r], om);
      S[r] = S[r] * exp2f(M[r] - nm) + os * exp2f(om - nm);
      M[r] = nm;
    }
  }
}

// ============================================================
// Persistent Sinkhorn. 256 blocks x 512 threads (8 waves), 1 block/CU.
// LDS (152KB): sxT[16][2048] + a2[2048] + wl2[2048] + q[2048] + red[8].
// ============================================================
__global__ __launch_bounds__(512, 2) void ot_sinkhorn(float* __restrict__ ws,
                                                      const float* __restrict__ wlog) {
  extern __shared__ float lds[];
  float* s_xt  = lds;                 // [16][2048]
  float* s_a2  = lds + 16 * 2048;     // [2048]
  float* s_wl2 = s_a2 + 2048;         // [2048]
  float* s_q   = s_wl2 + 2048;        // [2048]
  float* s_red = s_q + 2048;          // [8]

  const int bid = blockIdx.x;
  const int b  = bid >> 6;            // 64 blocks / batch
  const int rb = bid & 63;
  const int tid = threadIdx.x;
  const int w = tid >> 6, l = tid & 63;

  const float* __restrict__ sx = ws + OFF_SX + b * NPTS * DIM;
  const float* __restrict__ sq = ws + OFF_SQ + b * NPTS;
  float* fv = ws + OFF_F + b * NPTS;
  float* gv = ws + OFF_G + b * NPTS;
  const float* __restrict__ wl = wlog + b * NPTS;
  int* sy = (int*)ws + OFF_SYNC + b * 128;
  unsigned int* up2 = (unsigned int*)sy + 2;

  // ---- one-time LDS staging: transposed sx, wl*log2e, q
  for (int j = tid; j < NPTS; j += 512) {
    const float4* rp = (const float4*)(sx + j * DIM);
    float4 t0 = rp[0], t1 = rp[1], t2 = rp[2], t3 = rp[3];
    s_xt[ 0*2048+j]=t0.x; s_xt[ 1*2048+j]=t0.y; s_xt[ 2*2048+j]=t0.z; s_xt[ 3*2048+j]=t0.w;
    s_xt[ 4*2048+j]=t1.x; s_xt[ 5*2048+j]=t1.y; s_xt[ 6*2048+j]=t1.z; s_xt[ 7*2048+j]=t1.w;
    s_xt[ 8*2048+j]=t2.x; s_xt[ 9*2048+j]=t2.y; s_xt[10*2048+j]=t2.z; s_xt[11*2048+j]=t2.w;
    s_xt[12*2048+j]=t3.x; s_xt[13*2048+j]=t3.y; s_xt[14*2048+j]=t3.z; s_xt[15*2048+j]=t3.w;
    s_wl2[j] = wl[j] * L2E;
    s_q[j]   = sq[j];
  }
  const int row0 = rb * 32 + w * 4;
  const float qi_own = (l < 4) ? sq[row0 + l] : 0.f;   // own-row |sx|^2
  float fprev = 0.f, gprev = 0.f;                       // own-row f/g (l<4)
  float eps = ws[OFF_EPS0 + b];
  __syncthreads();

  int ph = 0;
  for (int it = 0; it < MAXIT; ++it) {
    const float le      = L2E / eps;
    const float eln2    = eps * LN2;
    const float inv_eps = 1.0f / eps;
    const bool  check   = (eps <= REGEPS);   // conv possible only then (ref: & eps2<=REG)

    // ---- row operands reloaded EVERY phase (short live range -> VGPRs).
    // volatile defeats LICM so they never live across barriers (proven fix
    // for the AGPR-eviction pathology: VGPR_Count 64 -> 128).
    float sxr[4][16];
    {
      const volatile float* vxt = s_xt;
      #pragma unroll
      for (int r = 0; r < 4; ++r)
        #pragma unroll
        for (int dd = 0; dd < 16; ++dd)
          sxr[r][dd] = vxt[dd * 2048 + row0 + r] * (2.0f * L2E);
    }

    // ================= F phase (src = g) =================
    {
      const int j4 = tid * 4;
      const float4 g4 = load_f4_coherent(gv + j4);
      const float4 q4 = *(const float4*)(s_q + j4);
      *(float4*)(s_a2 + j4) = make_float4((g4.x - q4.x) * le, (g4.y - q4.y) * le,
                                          (g4.z - q4.z) * le, (g4.w - q4.w) * le);
    }
    __syncthreads();
    {
      float M[4], S[4];
      lse_sweep(s_xt, s_a2, sxr, inv_eps, l, M, S);
      lse_butterfly(M, S);
      float updv = 0.f;
      if (l < 4) {
        const float Mr = (l==0)?M[0]:(l==1)?M[1]:(l==2)?M[2]:M[3];
        const float Sr = (l==0)?S[0]:(l==1)?S[1]:(l==2)?S[2]:S[3];
        const float fnew = fmaf(eps, LOGN, qi_own) - eln2 * (Mr + log2f(Sr));
        __hip_atomic_store(fv + row0 + l, fnew, __ATOMIC_RELEASE, __HIP_MEMORY_SCOPE_AGENT);
        updv = fabsf(fnew - fprev);
        fprev = fnew;
      }
      if (check) {
        updv = fmaxf(updv, __shfl_xor(updv, 1));
        updv = fmaxf(updv, __shfl_xor(updv, 2));
        if (l == 0) s_red[w] = updv;
      }
    }
    if (check) {
      __syncthreads();
      if (tid == 0) {
        float u = s_red[0];
        #pragma unroll
        for (int k = 1; k < 8; ++k) u = fmaxf(u, s_red[k]);
        __hip_atomic_fetch_max(up2 + (it & 1), __float_as_uint(u),
                               __ATOMIC_RELAXED, __HIP_MEMORY_SCOPE_AGENT);
      }
    }
    ++ph; batch_barrier(sy, ph);

    // ================= G phase (src = f, + log_a) =================
    if (rb == 0 && tid == 0)
      __hip_atomic_store(up2 + ((it + 1) & 1), 0u, __ATOMIC_RELAXED, __HIP_MEMORY_SCOPE_AGENT);
    {
      const int j4 = tid * 4;
      const float4 f4 = load_f4_coherent(fv + j4);
      const float4 q4 = *(const float4*)(s_q + j4);
      const float4 w2 = *(const float4*)(s_wl2 + j4);
      *(float4*)(s_a2 + j4) = make_float4(fmaf(f4.x - q4.x, le, w2.x), fmaf(f4.y - q4.y, le, w2.y),
                                          fmaf(f4.z - q4.z, le, w2.z), fmaf(f4.w - q4.w, le, w2.w));
    }
    __syncthreads();
    {
      float M[4], S[4];
      lse_sweep(s_xt, s_a2, sxr, inv_eps, l, M, S);
      lse_butterfly(M, S);
      float updv = 0.f;
      if (l < 4) {
        const float Mr = (l==0)?M[0]:(l==1)?M[1]:(l==2)?M[2]:M[3];
        const float Sr = (l==0)?S[0]:(l==1)?S[1]:(l==2)?S[2]:S[3];
        const float gnew = qi_own - eln2 * (Mr + log2f(Sr));
        __hip_atomic_store(gv + row0 + l, gnew, __ATOMIC_RELEASE, __HIP_MEMORY_SCOPE_AGENT);
        updv = fabsf(gnew - gprev);
        gprev = gnew;
      }
      if (check) {
        updv = fmaxf(updv, __shfl_xor(updv, 1));
        updv = fmaxf(updv, __shfl_xor(updv, 2));
        if (l == 0) s_red[w] = updv;
      }
    }
    if (check) {
      __syncthreads();
      if (tid == 0) {
        float u = s_red[0];
        #pragma unroll
        for (int k = 1; k < 8; ++k) u = fmaxf(u, s_red[k]);
        __hip_atomic_fetch_max(up2 + (it & 1), __float_as_uint(u),
                               __ATOMIC_RELAXED, __HIP_MEMORY_SCOPE_AGENT);
      }
    }
    if (it < MAXIT - 1) {
      ++ph; batch_barrier(sy, ph);
      if (check) {
        const unsigned uu = __hip_atomic_load(up2 + (it & 1), __ATOMIC_RELAXED, __HIP_MEMORY_SCOPE_AGENT);
        if (__uint_as_float(uu) < MINUPD) break;   // conv: upd<MIN && eps2<=REG (check==true)
      }
      eps = fmaxf(eps * DECAYF, REGEPS);
    }
  }
}

// ============================================================
// Output (proven): new_state + uniform_log_w.
// grid = BATCH * (NPTS/8) = 1024 blocks x 256 threads.
// ============================================================
__global__ __launch_bounds__(256) void ot_out(float* __restrict__ ws,
                                              const float* __restrict__ wlog,
                                              float* __restrict__ out) {
  __shared__ float s_xt[DIM][256];
  __shared__ float s_p[256];
  __shared__ float s_q[256];
  const int bid = blockIdx.x;
  const int b  = bid >> 8;
  const int rb = bid & 255;
  const int tid = threadIdx.x;
  const int w = tid >> 6, l = tid & 63;
  const float invR = 1.0f / REGEPS;

  const float* __restrict__ sx = ws + OFF_SX + b * NPTS * DIM;
  const float* __restrict__ sq = ws + OFF_SQ + b * NPTS;
  const float* __restrict__ fv = ws + OFF_F + b * NPTS;
  const float* __restrict__ gv = ws + OFF_G + b * NPTS;
  const float* __restrict__ wl = wlog + b * NPTS;

  const int row0 = rb * 8 + w * 2;
  float sxm[2][DIM], cm2[2], qm[2], acc[2][DIM], accT[2];
  #pragma unroll
  for (int r = 0; r < 2; ++r) {
    const int mrow = row0 + r;
    cm2[r] = sq[mrow];
    qm[r]  = gv[mrow] * invR;
    const float4* rp = (const float4*)(sx + mrow * DIM);
    #pragma unroll
    for (int c4 = 0; c4 < 4; ++c4) {
      float4 t = rp[c4];
      sxm[r][c4*4+0] = -2.0f * t.x; sxm[r][c4*4+1] = -2.0f * t.y;
      sxm[r][c4*4+2] = -2.0f * t.z; sxm[r][c4*4+3] = -2.0f * t.w;
    }
    #pragma unroll
    for (int dd = 0; dd < DIM; ++dd) acc[r][dd] = 0.0f;
    accT[r] = 0.0f;
  }

  for (int k = 0; k < NPTS / 256; ++k) {
    __syncthreads();
    {
      const int n = k * 256 + tid;
      const float4* rp = (const float4*)(sx + n * DIM);
      float4 t0 = rp[0], t1 = rp[1], t2 = rp[2], t3 = rp[3];
      s_xt[0][tid]=t0.x;  s_xt[1][tid]=t0.y;  s_xt[2][tid]=t0.z;  s_xt[3][tid]=t0.w;
      s_xt[4][tid]=t1.x;  s_xt[5][tid]=t1.y;  s_xt[6][tid]=t1.z;  s_xt[7][tid]=t1.w;
      s_xt[8][tid]=t2.x;  s_xt[9][tid]=t2.y;  s_xt[10][tid]=t2.z; s_xt[11][tid]=t2.w;
      s_xt[12][tid]=t3.x; s_xt[13][tid]=t3.y; s_xt[14][tid]=t3.z; s_xt[15][tid]=t3.w;
      s_q[tid] = sq[n];
      s_p[tid] = wl[n] - LOGN + fv[n] * invR;
    }
    __syncthreads();
    const float4 pv = *(const float4*)&s_p[4 * l];
    const float4 qv = *(const float4*)&s_q[4 * l];
    float a2[2][4];
    #pragma unroll
    for (int r = 0; r < 2; ++r) {
      a2[r][0] = cm2[r] + qv.x; a2[r][1] = cm2[r] + qv.y;
      a2[r][2] = cm2[r] + qv.z; a2[r][3] = cm2[r] + qv.w;
    }
    #pragma unroll
    for (int dd = 0; dd < DIM; ++dd) {
      const float4 xj = *(const float4*)&s_xt[dd][4 * l];
      #pragma unroll
      for (int r = 0; r < 2; ++r) {
        const float xr = sxm[r][dd];
        a2[r][0] = fmaf(xr, xj.x, a2[r][0]);
        a2[r][1] = fmaf(xr, xj.y, a2[r][1]);
        a2[r][2] = fmaf(xr, xj.z, a2[r][2]);
        a2[r][3] = fmaf(xr, xj.w, a2[r][3]);
      }
    }
    float T[2][4];
    #pragma unroll
    for (int r = 0; r < 2; ++r) {
      T[r][0] = __expf(fmaf(fmaxf(a2[r][0], 0.f), -invR, pv.x + qm[r]));
      T[r][1] = __expf(fmaf(fmaxf(a2[r][1], 0.f), -invR, pv.y + qm[r]));
      T[r][2] = __expf(fmaf(fmaxf(a2[r][2], 0.f), -invR, pv.z + qm[r]));
      T[r][3] = __expf(fmaf(fmaxf(a2[r][3], 0.f), -invR, pv.w + qm[r]));
      accT[r] += (T[r][0] + T[r][1]) + (T[r][2] + T[r][3]);
    }
    #pragma unroll
    for (int dd = 0; dd < DIM; ++dd) {
      const float4 xj = *(const float4*)&s_xt[dd][4 * l];
      #pragma unroll
      for (int r = 0; r < 2; ++r) {
        float t = acc[r][dd];
        t = fmaf(T[r][0], xj.x, t);
        t = fmaf(T[r][1], xj.y, t);
        t = fmaf(T[r][2], xj.z, t);
        t = fmaf(T[r][3], xj.w, t);
        acc[r][dd] = t;
      }
    }
  }
  #pragma unroll
  for (int off = 1; off < 64; off <<= 1) {
    #pragma unroll
    for (int r = 0; r < 2; ++r) {
      #pragma unroll
      for (int dd = 0; dd < DIM; ++dd) acc[r][dd] += __shfl_xor(acc[r][dd], off);
      accT[r] += __shfl_xor(accT[r], off);
    }
  }
  if (l == 0) {
    const float scale = ws[OFF_SCALE + b];
    const float* mean = ws + OFF_MEAN + b * DIM;
    #pragma unroll
    for (int r = 0; r < 2; ++r) {
      const int mrow = row0 + r;
      float ov[16];
      #pragma unroll
      for (int dd = 0; dd < DIM; ++dd)
        ov[dd] = (float)NPTS * fmaf(scale, acc[r][dd], mean[dd] * accT[r]);
      float4* op = (float4*)(out + (b * NPTS + mrow) * DIM);
      op[0] = make_float4(ov[0],ov[1],ov[2],ov[3]);
      op[1] = make_float4(ov[4],ov[5],ov[6],ov[7]);
      op[2] = make_float4(ov[8],ov[9],ov[10],ov[11]);
      op[3] = make_float4(ov[12],ov[13],ov[14],ov[15]);
    }
  }
  if (tid < 8) out[BATCH * NPTS * DIM + b * NPTS + rb * 8 + tid] = -LOGN;
}

extern "C" void kernel_launch(void* const* d_in, const int* in_sizes, int n_in,
                              void* d_out, int out_size, void* d_ws, size_t ws_size,
                              hipStream_t stream) {
  (void)in_sizes; (void)n_in; (void)out_size; (void)ws_size;
  const float* state  = (const float*)d_in[0];
  const float* weight = (const float*)d_in[1];
  float* out = (float*)d_out;
  float* ws  = (float*)d_ws;

  ot_preproc<<<dim3(BATCH), dim3(256), 0, stream>>>(state, ws);

  // LDS: sxT 128K + a2 8K + wl2 8K + q 8K + red 32B = 155680 B (1 block/CU)
  const unsigned int dynLds = (16 * 2048 + 3 * 2048 + 8) * 4;
  (void)hipFuncSetAttribute((const void*)ot_sinkhorn,
                            hipFuncAttributeMaxDynamicSharedMemorySize, (int)dynLds);
  hipLaunchKernelGGL(ot_sinkhorn, dim3(256), dim3(512), dynLds, stream, ws, weight);

  ot_out<<<dim3(BATCH * NPTS / 8), dim3(256), 0, stream>>>(ws, weight, out);
}

// Round 11
// 3634.644 us; speedup vs baseline: 1.0663x; 1.0663x over previous
//
#include <hip/hip_runtime.h>

#define BATCH 4
#define NPTS  2048
#define DIM   16
#define REGEPS 0.01f
#define DECAYF 0.9f
#define MINUPD 0.01f
#define MAXIT  50
#define LOGN   7.62461898616f   // ln(2048)
#define L2E    1.44269504089f   // log2(e)
#define LN2    0.69314718056f

typedef float v2f __attribute__((ext_vector_type(2)));

// ---- workspace layout (units of 4 bytes) ----
#define OFF_SX    0
#define OFF_SQ    (BATCH*NPTS*DIM)            // 131072
#define OFF_F     (OFF_SQ + BATCH*NPTS)       // 139264
#define OFF_G     (OFF_F + BATCH*NPTS)        // 147456
#define OFF_MEAN  (OFF_G + BATCH*NPTS)        // 155648
#define OFF_SCALE (OFF_MEAN + BATCH*DIM)      // 155712
#define OFF_EPS0  (OFF_SCALE + BATCH)         // 155716
// per-batch sync region: 128 ints (512B), 256B-aligned. R3-proven layout:
//   [0]   : arrive counter (acq_rel RMW by 64 blocks)   } line 0
//   [2,3] : upd dual slots (uint atomicMax every phase) } line 0
//   [32]  : epoch (1 writer, relaxed pollers, acq exit) } line 1
#define OFF_SYNC  155776                      // 623104 B

// ============================================================
// Preprocess (proven): mean/std/scale, sx, sq, extent->eps0,
// zero f/g, init sync region.  grid = BATCH x 256
// ============================================================
__global__ __launch_bounds__(256) void ot_preproc(const float* __restrict__ state,
                                                  float* __restrict__ ws) {
  const int b = blockIdx.x;
  const int tid = threadIdx.x;
  __shared__ float s_sum[16][17];
  __shared__ float s_sq[16][17];
  __shared__ float s_mean[16];
  __shared__ float s_red[8];
  __shared__ float s_scale_sh;

  const float* st = state + b * NPTS * DIM;
  const int d = tid & 15, grp = tid >> 4;
  float sm = 0.f, s2 = 0.f;
  for (int n = grp; n < NPTS; n += 16) {
    float x = st[n * DIM + d];
    sm += x; s2 += x * x;
  }
  s_sum[grp][d] = sm; s_sq[grp][d] = s2;
  __syncthreads();
  if (tid < 16) {
    float S = 0.f, Q = 0.f;
    for (int g2 = 0; g2 < 16; ++g2) { S += s_sum[g2][tid]; Q += s_sq[g2][tid]; }
    float mean = S * (1.0f / NPTS);
    float var  = fmaxf(Q * (1.0f / NPTS) - mean * mean, 0.f);
    float sd   = sqrtf(var);
    s_mean[tid] = mean;
    ws[OFF_MEAN + b * DIM + tid] = mean;
    s_sum[0][tid] = sd;
  }
  __syncthreads();
  if (tid == 0) {
    float dm = 0.f;
    for (int d2 = 0; d2 < 16; ++d2) dm = fmaxf(dm, s_sum[0][d2]);
    if (dm == 0.f) dm = 1.f;
    float scale = dm * 4.0f;          // * sqrt(D=16)
    s_scale_sh = scale;
    ws[OFF_SCALE + b] = scale;
  }
  __syncthreads();

  const float inv_scale = 1.0f / s_scale_sh;
  float vmin = 3.0e38f, vmax = -3.0e38f;
  float* sx = ws + OFF_SX + b * NPTS * DIM;
  float* sq = ws + OFF_SQ + b * NPTS;
  for (int n = tid; n < NPTS; n += 256) {
    const float4* rp = (const float4*)(st + n * DIM);
    float4 xs0 = rp[0], xs1 = rp[1], xs2 = rp[2], xs3 = rp[3];
    float xv[16] = {xs0.x,xs0.y,xs0.z,xs0.w, xs1.x,xs1.y,xs1.z,xs1.w,
                    xs2.x,xs2.y,xs2.z,xs2.w, xs3.x,xs3.y,xs3.z,xs3.w};
    float ov[16];
    float q = 0.f;
    #pragma unroll
    for (int e = 0; e < 16; ++e) {
      float v = (xv[e] - s_mean[e]) * inv_scale;
      ov[e] = v; q += v * v;
      vmin = fminf(vmin, v); vmax = fmaxf(vmax, v);
    }
    float4* op = (float4*)(sx + n * DIM);
    op[0] = make_float4(ov[0],ov[1],ov[2],ov[3]);
    op[1] = make_float4(ov[4],ov[5],ov[6],ov[7]);
    op[2] = make_float4(ov[8],ov[9],ov[10],ov[11]);
    op[3] = make_float4(ov[12],ov[13],ov[14],ov[15]);
    sq[n] = q;
  }
  float* fv = ws + OFF_F + b * NPTS;
  float* gv = ws + OFF_G + b * NPTS;
  for (int n = tid; n < NPTS; n += 256) { fv[n] = 0.f; gv[n] = 0.f; }
  #pragma unroll
  for (int off = 32; off > 0; off >>= 1) {
    vmin = fminf(vmin, __shfl_xor(vmin, off));
    vmax = fmaxf(vmax, __shfl_xor(vmax, off));
  }
  const int wv = tid >> 6, ln = tid & 63;
  if (ln == 0) { s_red[wv] = vmin; s_red[4 + wv] = vmax; }
  __syncthreads();
  if (tid == 0) {
    float mn = fminf(fminf(s_red[0], s_red[1]), fminf(s_red[2], s_red[3]));
    float mx = fmaxf(fmaxf(s_red[4], s_red[5]), fmaxf(s_red[6], s_red[7]));
    ws[OFF_EPS0 + b] = mx - mn;
  }
  // zero sync region (arrive/upd/epoch)
  int* sy = (int*)ws + OFF_SYNC + b * 128;
  for (int k = tid; k < 128; k += 256) sy[k] = 0;
}

// ============================================================
// Coherent (cross-XCD) 16B load: bypass L1/L2 (proven R3/R4 form).
// ============================================================
__device__ __forceinline__ float4 load_f4_coherent(const float* p) {
  float4 v;
  asm volatile("global_load_dwordx4 %0, %1, off sc0 sc1\n\t"
               "s_waitcnt vmcnt(0)"
               : "=v"(v) : "v"(p) : "memory");
  return v;
}

// ============================================================
// R3-proven epoch-broadcast barrier among 64 blocks of one batch.
// ============================================================
__device__ __forceinline__ void batch_barrier(int* sy, int ph) {
  __syncthreads();
  if (threadIdx.x == 0) {
    int* arrive = sy;
    int* epoch  = sy + 32;
    const int old = __hip_atomic_fetch_add(arrive, 1, __ATOMIC_ACQ_REL,
                                           __HIP_MEMORY_SCOPE_AGENT);
    if (old == 64 * ph - 1) {
      __hip_atomic_store(epoch, ph, __ATOMIC_RELEASE, __HIP_MEMORY_SCOPE_AGENT);
    } else {
      while (__hip_atomic_load(epoch, __ATOMIC_RELAXED, __HIP_MEMORY_SCOPE_AGENT) < ph)
        __builtin_amdgcn_s_sleep(2);
      (void)__hip_atomic_load(epoch, __ATOMIC_ACQUIRE, __HIP_MEMORY_SCOPE_AGENT);
    }
  }
  __syncthreads();
}

// ============================================================
// LSE sweep: float4 (b128) LDS loads — proven conflict-free pattern —
// reinterpreted as v2f pairs in-register for packed FMA.
// sxr holds 2*L2E*sx_i; a2 carries (src-q)*L2E/eps [+wl2].
// ============================================================
__device__ __forceinline__ void lse_sweep(const float* __restrict__ s_xt,
                                          const float* __restrict__ s_a2,
                                          const float (&sxr)[4][16],
                                          float inv_eps, int l,
                                          float (&M)[4], float (&S)[4]) {
  const v2f inv2 = { inv_eps, inv_eps };
  #pragma unroll
  for (int r = 0; r < 4; ++r) { M[r] = -3.0e38f; S[r] = 0.0f; }
  for (int c = 0; c < 8; ++c) {
    const int jb = c * 256 + 4 * l;
    const float4 af = *(const float4*)(s_a2 + jb);
    const v2f av0 = { af.x, af.y }, av1 = { af.z, af.w };
    v2f acc[4][2];
    {
      const float4 xf = *(const float4*)(s_xt + jb);   // dd = 0, ds_read_b128
      const v2f x0 = { xf.x, xf.y }, x1 = { xf.z, xf.w };
      #pragma unroll
      for (int r = 0; r < 4; ++r) {
        const v2f sv = { sxr[r][0], sxr[r][0] };
        acc[r][0] = x0 * sv;
        acc[r][1] = x1 * sv;
      }
    }
    #pragma unroll
    for (int dd = 1; dd < 16; ++dd) {
      const float4 xf = *(const float4*)(s_xt + dd * 2048 + jb);
      const v2f x0 = { xf.x, xf.y }, x1 = { xf.z, xf.w };
      #pragma unroll
      for (int r = 0; r < 4; ++r) {
        const v2f sv = { sxr[r][dd], sxr[r][dd] };
        acc[r][0] = __builtin_elementwise_fma(x0, sv, acc[r][0]);
        acc[r][1] = __builtin_elementwise_fma(x1, sv, acc[r][1]);
      }
    }
    #pragma unroll
    for (int r = 0; r < 4; ++r) {
      const v2f v01 = __builtin_elementwise_fma(acc[r][0], inv2, av0);
      const v2f v23 = __builtin_elementwise_fma(acc[r][1], inv2, av1);
      const float v0 = v01.x, v1 = v01.y, v2 = v23.x, v3 = v23.y;
      const float cmx = fmaxf(fmaxf(v0, v1), fmaxf(v2, v3));
      const float nm = fmaxf(M[r], cmx);
      const float e0 = exp2f(M[r] - nm);
      const float sa = exp2f(v0-nm) + exp2f(v1-nm) + exp2f(v2-nm) + exp2f(v3-nm);
      S[r] = fmaf(S[r], e0, sa);
      M[r] = nm;
    }
  }
}

__device__ __forceinline__ void lse_butterfly(float (&M)[4], float (&S)[4]) {
  #pragma unroll
  for (int off = 1; off < 64; off <<= 1) {
    #pragma unroll
    for (int r = 0; r < 4; ++r) {
      const float om = __shfl_xor(M[r], off);
      const float os = __shfl_xor(S[r], off);
      const float nm = fmaxf(M[r], om);
      S[r] = S[r] * exp2f(M[r] - nm) + os * exp2f(om - nm);
      M[r] = nm;
    }
  }
}

// ============================================================
// Persistent Sinkhorn. 256 blocks x 512 threads (8 waves), 1 block/CU.
// LDS (152KB): sxT[16][2048] + a2[2048] + wl2[2048] + q[2048] + red[8].
// ============================================================
__global__ __launch_bounds__(512, 2) void ot_sinkhorn(float* __restrict__ ws,
                                                      const float* __restrict__ wlog) {
  extern __shared__ float lds[];
  float* s_xt  = lds;                 // [16][2048]
  float* s_a2  = lds + 16 * 2048;     // [2048]
  float* s_wl2 = s_a2 + 2048;         // [2048]
  float* s_q   = s_wl2 + 2048;        // [2048]

  const int bid = blockIdx.x;
  const int b  = bid >> 6;            // 64 blocks / batch
  const int rb = bid & 63;
  const int tid = threadIdx.x;
  const int w = tid >> 6, l = tid & 63;

  const float* __restrict__ sx = ws + OFF_SX + b * NPTS * DIM;
  const float* __restrict__ sq = ws + OFF_SQ + b * NPTS;
  float* fv = ws + OFF_F + b * NPTS;
  float* gv = ws + OFF_G + b * NPTS;
  const float* __restrict__ wl = wlog + b * NPTS;
  int* sy = (int*)ws + OFF_SYNC + b * 128;
  unsigned int* up2 = (unsigned int*)sy + 2;

  // ---- one-time LDS staging: transposed sx, wl*log2e, q
  for (int j = tid; j < NPTS; j += 512) {
    const float4* rp = (const float4*)(sx + j * DIM);
    float4 t0 = rp[0], t1 = rp[1], t2 = rp[2], t3 = rp[3];
    s_xt[ 0*2048+j]=t0.x; s_xt[ 1*2048+j]=t0.y; s_xt[ 2*2048+j]=t0.z; s_xt[ 3*2048+j]=t0.w;
    s_xt[ 4*2048+j]=t1.x; s_xt[ 5*2048+j]=t1.y; s_xt[ 6*2048+j]=t1.z; s_xt[ 7*2048+j]=t1.w;
    s_xt[ 8*2048+j]=t2.x; s_xt[ 9*2048+j]=t2.y; s_xt[10*2048+j]=t2.z; s_xt[11*2048+j]=t2.w;
    s_xt[12*2048+j]=t3.x; s_xt[13*2048+j]=t3.y; s_xt[14*2048+j]=t3.z; s_xt[15*2048+j]=t3.w;
    s_wl2[j] = wl[j] * L2E;
    s_q[j]   = sq[j];
  }
  const int row0 = rb * 32 + w * 4;
  const float qi_own = (l < 4) ? sq[row0 + l] : 0.f;   // own-row |sx|^2
  float eps = ws[OFF_EPS0 + b];
  __syncthreads();

  int ph = 0;
  for (int it = 0; it < MAXIT; ++it) {
    const float le      = L2E / eps;
    const float eln2    = eps * LN2;
    const float inv_eps = 1.0f / eps;

    // ---- row operands reloaded EVERY phase (short live range -> VGPRs).
    // volatile defeats LICM so they never live across barriers (proven fix
    // for the AGPR-eviction pathology: VGPR_Count 64 -> 128).
    float sxr[4][16];
    {
      const volatile float* vxt = s_xt;
      #pragma unroll
      for (int r = 0; r < 4; ++r)
        #pragma unroll
        for (int dd = 0; dd < 16; ++dd)
          sxr[r][dd] = vxt[dd * 2048 + row0 + r] * (2.0f * L2E);
    }

    // ================= F phase (src = g) =================
    {
      const int j4 = tid * 4;
      const float4 g4 = load_f4_coherent(gv + j4);
      const float4 q4 = *(const float4*)(s_q + j4);
      *(float4*)(s_a2 + j4) = make_float4((g4.x - q4.x) * le, (g4.y - q4.y) * le,
                                          (g4.z - q4.z) * le, (g4.w - q4.w) * le);
    }
    __syncthreads();
    {
      float M[4], S[4];
      lse_sweep(s_xt, s_a2, sxr, inv_eps, l, M, S);
      lse_butterfly(M, S);
      if (l < 4) {
        const float Mr = (l==0)?M[0]:(l==1)?M[1]:(l==2)?M[2]:M[3];
        const float Sr = (l==0)?S[0]:(l==1)?S[1]:(l==2)?S[2]:S[3];
        const int i = row0 + l;
        const float fnew = fmaf(eps, LOGN, qi_own) - eln2 * (Mr + log2f(Sr));
        // R3/R4-proven exchange-update: load old (installs line) -> store ->
        // per-lane atomicMax. This pattern measured FETCH ~17MB vs 150-230MB
        // for the blind-store variants (R7-R9).
        const float old = __hip_atomic_load(fv + i, __ATOMIC_RELAXED, __HIP_MEMORY_SCOPE_AGENT);
        __hip_atomic_store(fv + i, fnew, __ATOMIC_RELEASE, __HIP_MEMORY_SCOPE_AGENT);
        __hip_atomic_fetch_max(up2 + (it & 1), __float_as_uint(fabsf(fnew - old)),
                               __ATOMIC_RELAXED, __HIP_MEMORY_SCOPE_AGENT);
      }
    }
    ++ph; batch_barrier(sy, ph);

    // ================= G phase (src = f, + log_a) =================
    if (rb == 0 && tid == 0)
      __hip_atomic_store(up2 + ((it + 1) & 1), 0u, __ATOMIC_RELAXED, __HIP_MEMORY_SCOPE_AGENT);
    {
      const int j4 = tid * 4;
      const float4 f4 = load_f4_coherent(fv + j4);
      const float4 q4 = *(const float4*)(s_q + j4);
      const float4 w2 = *(const float4*)(s_wl2 + j4);
      *(float4*)(s_a2 + j4) = make_float4(fmaf(f4.x - q4.x, le, w2.x), fmaf(f4.y - q4.y, le, w2.y),
                                          fmaf(f4.z - q4.z, le, w2.z), fmaf(f4.w - q4.w, le, w2.w));
    }
    __syncthreads();
    {
      float M[4], S[4];
      lse_sweep(s_xt, s_a2, sxr, inv_eps, l, M, S);
      lse_butterfly(M, S);
      if (l < 4) {
        const float Mr = (l==0)?M[0]:(l==1)?M[1]:(l==2)?M[2]:M[3];
        const float Sr = (l==0)?S[0]:(l==1)?S[1]:(l==2)?S[2]:S[3];
        const int i = row0 + l;
        const float gnew = qi_own - eln2 * (Mr + log2f(Sr));
        const float old = __hip_atomic_load(gv + i, __ATOMIC_RELAXED, __HIP_MEMORY_SCOPE_AGENT);
        __hip_atomic_store(gv + i, gnew, __ATOMIC_RELEASE, __HIP_MEMORY_SCOPE_AGENT);
        __hip_atomic_fetch_max(up2 + (it & 1), __float_as_uint(fabsf(gnew - old)),
                               __ATOMIC_RELAXED, __HIP_MEMORY_SCOPE_AGENT);
      }
    }
    if (it < MAXIT - 1) {
      ++ph; batch_barrier(sy, ph);
      const unsigned uu = __hip_atomic_load(up2 + (it & 1), __ATOMIC_RELAXED, __HIP_MEMORY_SCOPE_AGENT);
      const bool conv = (__uint_as_float(uu) < MINUPD) && (eps <= REGEPS);  // eps = pre-update (ref eps2)
      if (conv) break;
      eps = fmaxf(eps * DECAYF, REGEPS);
    }
  }
}

// ============================================================
// Output (proven): new_state + uniform_log_w.
// grid = BATCH * (NPTS/8) = 1024 blocks x 256 threads.
// ============================================================
__global__ __launch_bounds__(256) void ot_out(float* __restrict__ ws,
                                              const float* __restrict__ wlog,
                                              float* __restrict__ out) {
  __shared__ float s_xt[DIM][256];
  __shared__ float s_p[256];
  __shared__ float s_q[256];
  const int bid = blockIdx.x;
  const int b  = bid >> 8;
  const int rb = bid & 255;
  const int tid = threadIdx.x;
  const int w = tid >> 6, l = tid & 63;
  const float invR = 1.0f / REGEPS;

  const float* __restrict__ sx = ws + OFF_SX + b * NPTS * DIM;
  const float* __restrict__ sq = ws + OFF_SQ + b * NPTS;
  const float* __restrict__ fv = ws + OFF_F + b * NPTS;
  const float* __restrict__ gv = ws + OFF_G + b * NPTS;
  const float* __restrict__ wl = wlog + b * NPTS;

  const int row0 = rb * 8 + w * 2;
  float sxm[2][DIM], cm2[2], qm[2], acc[2][DIM], accT[2];
  #pragma unroll
  for (int r = 0; r < 2; ++r) {
    const int mrow = row0 + r;
    cm2[r] = sq[mrow];
    qm[r]  = gv[mrow] * invR;
    const float4* rp = (const float4*)(sx + mrow * DIM);
    #pragma unroll
    for (int c4 = 0; c4 < 4; ++c4) {
      float4 t = rp[c4];
      sxm[r][c4*4+0] = -2.0f * t.x; sxm[r][c4*4+1] = -2.0f * t.y;
      sxm[r][c4*4+2] = -2.0f * t.z; sxm[r][c4*4+3] = -2.0f * t.w;
    }
    #pragma unroll
    for (int dd = 0; dd < DIM; ++dd) acc[r][dd] = 0.0f;
    accT[r] = 0.0f;
  }

  for (int k = 0; k < NPTS / 256; ++k) {
    __syncthreads();
    {
      const int n = k * 256 + tid;
      const float4* rp = (const float4*)(sx + n * DIM);
      float4 t0 = rp[0], t1 = rp[1], t2 = rp[2], t3 = rp[3];
      s_xt[0][tid]=t0.x;  s_xt[1][tid]=t0.y;  s_xt[2][tid]=t0.z;  s_xt[3][tid]=t0.w;
      s_xt[4][tid]=t1.x;  s_xt[5][tid]=t1.y;  s_xt[6][tid]=t1.z;  s_xt[7][tid]=t1.w;
      s_xt[8][tid]=t2.x;  s_xt[9][tid]=t2.y;  s_xt[10][tid]=t2.z; s_xt[11][tid]=t2.w;
      s_xt[12][tid]=t3.x; s_xt[13][tid]=t3.y; s_xt[14][tid]=t3.z; s_xt[15][tid]=t3.w;
      s_q[tid] = sq[n];
      s_p[tid] = wl[n] - LOGN + fv[n] * invR;
    }
    __syncthreads();
    const float4 pv = *(const float4*)&s_p[4 * l];
    const float4 qv = *(const float4*)&s_q[4 * l];
    float a2[2][4];
    #pragma unroll
    for (int r = 0; r < 2; ++r) {
      a2[r][0] = cm2[r] + qv.x; a2[r][1] = cm2[r] + qv.y;
      a2[r][2] = cm2[r] + qv.z; a2[r][3] = cm2[r] + qv.w;
    }
    #pragma unroll
    for (int dd = 0; dd < DIM; ++dd) {
      const float4 xj = *(const float4*)&s_xt[dd][4 * l];
      #pragma unroll
      for (int r = 0; r < 2; ++r) {
        const float xr = sxm[r][dd];
        a2[r][0] = fmaf(xr, xj.x, a2[r][0]);
        a2[r][1] = fmaf(xr, xj.y, a2[r][1]);
        a2[r][2] = fmaf(xr, xj.z, a2[r][2]);
        a2[r][3] = fmaf(xr, xj.w, a2[r][3]);
      }
    }
    float T[2][4];
    #pragma unroll
    for (int r = 0; r < 2; ++r) {
      T[r][0] = __expf(fmaf(fmaxf(a2[r][0], 0.f), -invR, pv.x + qm[r]));
      T[r][1] = __expf(fmaf(fmaxf(a2[r][1], 0.f), -invR, pv.y + qm[r]));
      T[r][2] = __expf(fmaf(fmaxf(a2[r][2], 0.f), -invR, pv.z + qm[r]));
      T[r][3] = __expf(fmaf(fmaxf(a2[r][3], 0.f), -invR, pv.w + qm[r]));
      accT[r] += (T[r][0] + T[r][1]) + (T[r][2] + T[r][3]);
    }
    #pragma unroll
    for (int dd = 0; dd < DIM; ++dd) {
      const float4 xj = *(const float4*)&s_xt[dd][4 * l];
      #pragma unroll
      for (int r = 0; r < 2; ++r) {
        float t = acc[r][dd];
        t = fmaf(T[r][0], xj.x, t);
        t = fmaf(T[r][1], xj.y, t);
        t = fmaf(T[r][2], xj.z, t);
        t = fmaf(T[r][3], xj.w, t);
        acc[r][dd] = t;
      }
    }
  }
  #pragma unroll
  for (int off = 1; off < 64; off <<= 1) {
    #pragma unroll
    for (int r = 0; r < 2; ++r) {
      #pragma unroll
      for (int dd = 0; dd < DIM; ++dd) acc[r][dd] += __shfl_xor(acc[r][dd], off);
      accT[r] += __shfl_xor(accT[r], off);
    }
  }
  if (l == 0) {
    const float scale = ws[OFF_SCALE + b];
    const float* mean = ws + OFF_MEAN + b * DIM;
    #pragma unroll
    for (int r = 0; r < 2; ++r) {
      const int mrow = row0 + r;
      float ov[16];
      #pragma unroll
      for (int dd = 0; dd < DIM; ++dd)
        ov[dd] = (float)NPTS * fmaf(scale, acc[r][dd], mean[dd] * accT[r]);
      float4* op = (float4*)(out + (b * NPTS + mrow) * DIM);
      op[0] = make_float4(ov[0],ov[1],ov[2],ov[3]);
      op[1] = make_float4(ov[4],ov[5],ov[6],ov[7]);
      op[2] = make_float4(ov[8],ov[9],ov[10],ov[11]);
      op[3] = make_float4(ov[12],ov[13],ov[14],ov[15]);
    }
  }
  if (tid < 8) out[BATCH * NPTS * DIM + b * NPTS + rb * 8 + tid] = -LOGN;
}

extern "C" void kernel_launch(void* const* d_in, const int* in_sizes, int n_in,
                              void* d_out, int out_size, void* d_ws, size_t ws_size,
                              hipStream_t stream) {
  (void)in_sizes; (void)n_in; (void)out_size; (void)ws_size;
  const float* state  = (const float*)d_in[0];
  const float* weight = (const float*)d_in[1];
  float* out = (float*)d_out;
  float* ws  = (float*)d_ws;

  ot_preproc<<<dim3(BATCH), dim3(256), 0, stream>>>(state, ws);

  // LDS: sxT 128K + a2 8K + wl2 8K + q 8K + 32B = 155680 B (1 block/CU)
  const unsigned int dynLds = (16 * 2048 + 3 * 2048 + 8) * 4;
  (void)hipFuncSetAttribute((const void*)ot_sinkhorn,
                            hipFuncAttributeMaxDynamicSharedMemorySize, (int)dynLds);
  hipLaunchKernelGGL(ot_sinkhorn, dim3(256), dim3(512), dynLds, stream, ws, weight);

  ot_out<<<dim3(BATCH * NPTS / 8), dim3(256), 0, stream>>>(ws, weight, out);
}